// Round 1
// baseline (58.791 us; speedup 1.0000x reference)
//
#include <hip/hip_runtime.h>

// Problem constants (from reference): B=16, S=4096, H=1024, NSEG=512
constexpr int B    = 16;
constexpr int S    = 4096;
constexpr int H    = 1024;
constexpr int NSEG = 512;

// One block per output row (b, seg). 256 threads, each owns 4 contiguous
// H-columns (H = 1024 = 256*4). output_mask is sorted non-decreasing per
// batch row, so the tokens of segment `seg` are the contiguous range
// [lower_bound(seg), lower_bound(seg+1)). Thread 0 binary-searches both
// bounds, broadcasts through LDS; then all threads do a dense float4
// accumulation over the range (fully coalesced: 64 lanes x 16B).
__global__ __launch_bounds__(256) void seg_mean_kernel(
    const float* __restrict__ hs,    // [B, S, H]
    const int*   __restrict__ mask,  // [B, S], sorted per row
    float*       __restrict__ out)   // [B*NSEG, H]
{
    const int gid = blockIdx.x;          // 0 .. B*NSEG-1
    const int b   = gid >> 9;            // / NSEG
    const int seg = gid & (NSEG - 1);

    __shared__ int s_start, s_end;
    if (threadIdx.x == 0) {
        const int* row = mask + b * S;
        // lower_bound(seg)
        int lo = 0, hi = S;
        while (lo < hi) {
            int mid = (lo + hi) >> 1;
            if (row[mid] < seg) lo = mid + 1; else hi = mid;
        }
        int start = lo;
        // lower_bound(seg+1), starting from `start`
        hi = S;
        while (lo < hi) {
            int mid = (lo + hi) >> 1;
            if (row[mid] < seg + 1) lo = mid + 1; else hi = mid;
        }
        s_start = start;
        s_end   = lo;
    }
    __syncthreads();

    const int start = s_start;
    const int cnt   = s_end - start;

    const int col = threadIdx.x << 2;    // 4 columns per thread
    float4 acc = make_float4(0.f, 0.f, 0.f, 0.f);

    const float* base = hs + ((size_t)b * S + (size_t)start) * H + col;
    for (int t = 0; t < cnt; ++t) {
        float4 v = *reinterpret_cast<const float4*>(base + (size_t)t * H);
        acc.x += v.x; acc.y += v.y; acc.z += v.z; acc.w += v.w;
    }

    const float inv = (cnt > 0) ? (1.0f / (float)cnt) : 0.0f;
    acc.x *= inv; acc.y *= inv; acc.z *= inv; acc.w *= inv;

    *reinterpret_cast<float4*>(out + (size_t)gid * H + col) = acc;
}

extern "C" void kernel_launch(void* const* d_in, const int* in_sizes, int n_in,
                              void* d_out, int out_size, void* d_ws, size_t ws_size,
                              hipStream_t stream) {
    const float* hs   = (const float*)d_in[0];  // hidden_states [B,S,H] f32
    const int*   mask = (const int*)  d_in[1];  // output_mask  [B,S] i32

    float* out = (float*)d_out;                 // [B*NSEG, H] f32

    dim3 grid(B * NSEG);
    dim3 block(256);
    seg_mean_kernel<<<grid, block, 0, stream>>>(hs, mask, out);
}

// Round 2
// 56.330 us; speedup vs baseline: 1.0437x; 1.0437x over previous
//
#include <hip/hip_runtime.h>

// Problem constants (from reference): B=16, S=4096, H=1024, NSEG=512
constexpr int B    = 16;
constexpr int S    = 4096;
constexpr int H    = 1024;
constexpr int NSEG = 512;

// ---------------------------------------------------------------------------
// Kernel 1: segment-boundary precompute.
// output_mask is sorted non-decreasing per batch row, so segment `seg`
// occupies the contiguous token range [bounds[seg], bounds[seg+1]).
// One thread per token: where the id changes between i-1 and i, all segments
// in (prev, cur] start at i. Thread S-1 additionally closes the tail.
// bounds layout: [B][NSEG+1] ints in d_ws (16*513*4 = 32,832 B).
// ---------------------------------------------------------------------------
__global__ __launch_bounds__(256) void seg_bounds_kernel(
    const int* __restrict__ mask,   // [B, S] sorted per row
    int*       __restrict__ bounds) // [B, NSEG+1]
{
    const int idx = blockIdx.x * blockDim.x + threadIdx.x;  // 0 .. B*S-1
    const int b = idx >> 12;          // / S (S = 4096)
    const int i = idx & (S - 1);

    const int* row  = mask + b * S;
    int*       brow = bounds + b * (NSEG + 1);

    int cur  = row[i];
    int prev = (i == 0) ? -1 : row[i - 1];

    // clamp to valid segment-id space (ids < 0 are "dropped" tokens)
    if (cur  > NSEG - 1) cur  = NSEG - 1;
    if (prev < -1)       prev = -1;

    for (int s = prev + 1; s <= cur; ++s) brow[s] = i;
    if (i == S - 1) {
        for (int s = (cur < 0 ? 0 : cur + 1); s <= NSEG; ++s) brow[s] = S;
    }
}

// ---------------------------------------------------------------------------
// Kernel 2: dense mean over the contiguous token range of each (b, seg).
// One block per output row. 256 threads * float4 = full 1024-col row per
// token (fully coalesced, 16 B/lane). 4x unrolled with two accumulators so
// 4 float4 HBM loads are in flight per thread.
// ---------------------------------------------------------------------------
__global__ __launch_bounds__(256) void seg_mean_kernel(
    const float* __restrict__ hs,     // [B, S, H]
    const int*   __restrict__ bounds, // [B, NSEG+1]
    float*       __restrict__ out)    // [B*NSEG, H]
{
    const int gid = blockIdx.x;          // 0 .. B*NSEG-1
    const int b   = gid >> 9;            // / NSEG
    const int seg = gid & (NSEG - 1);

    const int* brow  = bounds + b * (NSEG + 1);
    const int  start = brow[seg];        // broadcast load (same line all lanes)
    const int  end   = brow[seg + 1];
    const int  cnt   = end - start;

    const int col = threadIdx.x << 2;    // 4 columns per thread

    const float* base = hs + ((size_t)b * S + (size_t)start) * H + col;

    float4 a0 = make_float4(0.f, 0.f, 0.f, 0.f);
    float4 a1 = make_float4(0.f, 0.f, 0.f, 0.f);

    int t = 0;
    for (; t + 4 <= cnt; t += 4) {
        float4 v0 = *reinterpret_cast<const float4*>(base + (size_t)(t + 0) * H);
        float4 v1 = *reinterpret_cast<const float4*>(base + (size_t)(t + 1) * H);
        float4 v2 = *reinterpret_cast<const float4*>(base + (size_t)(t + 2) * H);
        float4 v3 = *reinterpret_cast<const float4*>(base + (size_t)(t + 3) * H);
        a0.x += v0.x; a0.y += v0.y; a0.z += v0.z; a0.w += v0.w;
        a1.x += v1.x; a1.y += v1.y; a1.z += v1.z; a1.w += v1.w;
        a0.x += v2.x; a0.y += v2.y; a0.z += v2.z; a0.w += v2.w;
        a1.x += v3.x; a1.y += v3.y; a1.z += v3.z; a1.w += v3.w;
    }
    for (; t < cnt; ++t) {
        float4 v = *reinterpret_cast<const float4*>(base + (size_t)t * H);
        a0.x += v.x; a0.y += v.y; a0.z += v.z; a0.w += v.w;
    }

    a0.x += a1.x; a0.y += a1.y; a0.z += a1.z; a0.w += a1.w;

    const float inv = (cnt > 0) ? (1.0f / (float)cnt) : 0.0f;
    a0.x *= inv; a0.y *= inv; a0.z *= inv; a0.w *= inv;

    *reinterpret_cast<float4*>(out + (size_t)gid * H + col) = a0;
}

extern "C" void kernel_launch(void* const* d_in, const int* in_sizes, int n_in,
                              void* d_out, int out_size, void* d_ws, size_t ws_size,
                              hipStream_t stream) {
    const float* hs   = (const float*)d_in[0];  // hidden_states [B,S,H] f32
    const int*   mask = (const int*)  d_in[1];  // output_mask  [B,S] i32

    float* out    = (float*)d_out;              // [B*NSEG, H] f32
    int*   bounds = (int*)d_ws;                 // [B, NSEG+1] i32 scratch

    seg_bounds_kernel<<<dim3((B * S) / 256), dim3(256), 0, stream>>>(mask, bounds);
    seg_mean_kernel <<<dim3(B * NSEG),       dim3(256), 0, stream>>>(hs, bounds, out);
}